// Round 17
// baseline (21.204 us; speedup 1.0000x reference)
//
#include <hip/hip_runtime.h>
#include <math.h>

// CapLayer fused, R17 = R16 + permlane32_swap (xor32 off the DS pipe and off
// the 60-cyc bperm latency chain) + pk-packed s-partial/u-dot/ssq.
// Model trail: R13 (-6%) DPP xor1/2; R15 (-6%) u-phase b128 + ror4/8;
// R16 (-11%) pk_fma on yp/b-update. Each DS/VALU cut lands ~50-100% visible.
// NO launch_bounds min-waves (R2/R3/R7: caps below working set spill).

#define G_    32
#define J_    10
#define D_    16
#define NT_   128
#define GSW_  148

typedef float v2f __attribute__((ext_vector_type(2)));

__device__ __forceinline__ v2f pk_fma(v2f a, v2f b, v2f c) {
    v2f d;
    asm("v_pk_fma_f32 %0, %1, %2, %3" : "=v"(d) : "v"(a), "v"(b), "v"(c));
    return d;
}
__device__ __forceinline__ v2f pk_add(v2f a, v2f b) {
    v2f d;
    asm("v_pk_add_f32 %0, %1, %2" : "=v"(d) : "v"(a), "v"(b));
    return d;
}
__device__ __forceinline__ v2f pk_mul(v2f a, v2f b) {
    v2f d;
    asm("v_pk_mul_f32 %0, %1, %2" : "=v"(d) : "v"(a), "v"(b));
    return d;
}
__device__ __forceinline__ v2f mk2(float a, float b) { v2f r; r.x = a; r.y = b; return r; }

__device__ __forceinline__ float dpp_add_x1(float v) {   // v += lane^1
    const int s = __builtin_amdgcn_update_dpp(0, __float_as_int(v), 0xB1, 0xF, 0xF, true);
    return v + __int_as_float(s);
}
__device__ __forceinline__ float dpp_add_x2(float v) {   // v += lane^2
    const int s = __builtin_amdgcn_update_dpp(0, __float_as_int(v), 0x4E, 0xF, 0xF, true);
    return v + __int_as_float(s);
}
__device__ __forceinline__ float dpp_add_ror4(float v) { // v += row_ror:4
    const int s = __builtin_amdgcn_update_dpp(0, __float_as_int(v), 0x124, 0xF, 0xF, true);
    return v + __int_as_float(s);
}
__device__ __forceinline__ float dpp_add_ror8(float v) { // v += row_ror:8
    const int s = __builtin_amdgcn_update_dpp(0, __float_as_int(v), 0x128, 0xF, 0xF, true);
    return v + __int_as_float(s);
}
__device__ __forceinline__ float pl32_add(float v) {     // v += lane^32 (VALU)
    float a = v, b = v;
    asm("v_permlane32_swap_b32 %0, %1" : "+v"(a), "+v"(b));
    return a + b;   // low lanes: v.lo+v.hi ; high lanes: v.lo+v.hi
}

__global__ __launch_bounds__(NT_) void caps_route_kernel(
    const float* __restrict__ x,     // (b, g*8+k, s) flat b*9216 + g*288 + k*36 + s
    const float* __restrict__ Wt,    // (g, j*16+d, k) flat g*1280 + (j*16+d)*8 + k
    const float* __restrict__ bias,  // g*160 + j*16 + d
    float* __restrict__ out)         // (b, j, d)
{
    const int B = blockIdx.x, nwg = gridDim.x;
    const int bj = ((nwg & 7) == 0) ? (B & 7) * (nwg >> 3) + (B >> 3) : B;
    const int b = bj / J_, j = bj - b * J_;
    const int t = threadIdx.x;
    const int lane = t & 63, wid = t >> 6;
    const int g = t >> 2, c = t & 3;     // group 0..31, 4 lanes/group

    __shared__ float Wk[G_ * GSW_];               // 18.9 KB, [g][k][d] (+bias k=8)
    __shared__ __align__(16) float swl[2][2][D_]; // [buf][wave][d] s-partials
    __shared__ float esw[2][2];                   // [buf][wave] exp-sum partials

    // ---- x preload as q-pairs ----
    v2f  xq2[8][4];
    float xq8[8];
    {
        const float* xb = x + (size_t)b * 9216 + (size_t)g * 288 + 4 * c;
        #pragma unroll
        for (int k = 0; k < 8; ++k) {
            const float4 a0 = *(const float4*)(xb + k * 36);
            const float4 a1 = *(const float4*)(xb + k * 36 + 16);
            xq2[k][0] = mk2(a0.x, a0.y); xq2[k][1] = mk2(a0.z, a0.w);
            xq2[k][2] = mk2(a1.x, a1.y); xq2[k][3] = mk2(a1.z, a1.w);
            xq8[k] = xb[k * 36 + 32 - 3 * c];   // = row + 32 + c
        }
    }

    // ---- stage Wk transposed ([g][k][d]) + bias as k=8 row ----
    #pragma unroll
    for (int rr = 0; rr < 4; ++rr) {
        const int idx = t + rr * NT_;
        const int gg = idx >> 4, d = idx & 15;
        const float* src = Wt + (size_t)gg * 1280 + j * 128 + d * 8;
        const float4 a0 = *(const float4*)(src);
        const float4 a1 = *(const float4*)(src + 4);
        float* dst = Wk + gg * GSW_ + d;
        dst[0]   = a0.x; dst[16]  = a0.y; dst[32]  = a0.z; dst[48]  = a0.w;
        dst[64]  = a1.x; dst[80]  = a1.y; dst[96]  = a1.z; dst[112] = a1.w;
        dst[128] = bias[gg * 160 + j * 16 + d];
    }
    __syncthreads();                               // barrier 0 (staging)

    v2f  bl2[4] = {mk2(0.f,0.f), mk2(0.f,0.f), mk2(0.f,0.f), mk2(0.f,0.f)};
    float bl8 = 0.f;
    const float EPS = 2.220446049250313e-16f;

    #pragma unroll 1
    for (int it = 0; it < 3; ++it) {
        const int kb = it & 1;

        // ---- e-weighted x sums (packed) ----
        float yp[8];
        float esum = 0.f;
        if (it == 0) {
            #pragma unroll
            for (int k = 0; k < 8; ++k) {
                v2f acc = pk_add(xq2[k][0], xq2[k][1]);
                acc = pk_add(acc, xq2[k][2]);
                acc = pk_add(acc, xq2[k][3]);
                yp[k] = acc.x + acc.y + xq8[k];
            }
        } else {
            v2f e2[4];
            #pragma unroll
            for (int p = 0; p < 4; ++p)
                e2[p] = mk2(__expf(bl2[p].x), __expf(bl2[p].y));
            const float e8 = __expf(bl8);
            v2f es2 = pk_add(pk_add(e2[0], e2[1]), pk_add(e2[2], e2[3]));
            esum = es2.x + es2.y + e8;
            #pragma unroll
            for (int k = 0; k < 8; ++k) {
                v2f acc = pk_mul(e2[0], xq2[k][0]);
                acc = pk_fma(e2[1], xq2[k][1], acc);
                acc = pk_fma(e2[2], xq2[k][2], acc);
                acc = pk_fma(e2[3], xq2[k][3], acc);
                yp[k] = acc.x + acc.y + e8 * xq8[k];
            }
        }
        // quad reduce via DPP
        #pragma unroll
        for (int k = 0; k < 8; ++k) {
            yp[k] = dpp_add_x1(yp[k]);
            yp[k] = dpp_add_x2(yp[k]);
        }
        if (it > 0) { esum = dpp_add_x1(esum); esum = dpp_add_x2(esum); }
        const float cg = (it == 0) ? 36.f : esum;

        // ---- per-lane s-partial for d = 4c..4c+3, pk-packed over d-pairs ----
        const float* wg = Wk + g * GSW_ + 4 * c;
        v2f part01, part23;
        {
            const float4 wb = *(const float4*)(wg + 128);   // bias row (k=8)
            const v2f cg2 = mk2(cg, cg);
            part01 = pk_mul(mk2(wb.x, wb.y), cg2);
            part23 = pk_mul(mk2(wb.z, wb.w), cg2);
            #pragma unroll
            for (int k = 0; k < 8; ++k) {
                const float4 wv = *(const float4*)(wg + k * 16);
                const v2f yp2 = mk2(yp[k], yp[k]);
                part01 = pk_fma(mk2(wv.x, wv.y), yp2, part01);
                part23 = pk_fma(mk2(wv.z, wv.w), yp2, part23);
            }
        }
        float part[4];
        part[0] = part01.x; part[1] = part01.y;
        part[2] = part23.x; part[3] = part23.y;
        // reduce over the wave's 16 groups: ror4/ror8 DPP, xor16 shfl,
        // xor32 via permlane32_swap (VALU, off the DS pipe)
        #pragma unroll
        for (int m = 0; m < 4; ++m) {
            part[m] = dpp_add_ror4(part[m]);
            part[m] = dpp_add_ror8(part[m]);
            part[m] += __shfl_xor(part[m], 16);
            part[m] = pl32_add(part[m]);
        }
        if (it > 0) {
            esum = dpp_add_ror4(esum);
            esum = dpp_add_ror8(esum);
            esum += __shfl_xor(esum, 16);
            esum = pl32_add(esum);
        }
        // lanes 0..3 hold s_w[4c..4c+3] (c == lane there)
        if (lane < 4) {
            float4 pw; pw.x = part[0]; pw.y = part[1]; pw.z = part[2]; pw.w = part[3];
            *(float4*)(&swl[kb][wid][4 * lane]) = pw;
            if (lane == 0) esw[kb][wid] = esum;
        }
        __syncthreads();                           // 1 barrier per iter

        const float denom = (it == 0) ? 1152.f : (esw[kb][0] + esw[kb][1]);

        // ---- this lane's s d-slice (broadcast b128 reads), pk-packed ----
        const float4 sa = *(const float4*)(&swl[kb][0][4 * c]);
        const float4 sb = *(const float4*)(&swl[kb][1][4 * c]);
        const v2f s01 = pk_add(mk2(sa.x, sa.y), mk2(sb.x, sb.y));
        const v2f s23 = pk_add(mk2(sa.z, sa.w), mk2(sb.z, sb.w));

        // ssq: slice partial + DPP quad reduce
        v2f ss2 = pk_mul(s01, s01);
        ss2 = pk_fma(s23, s23, ss2);
        float ssq = ss2.x + ss2.y;
        ssq = dpp_add_x1(ssq);
        ssq = dpp_add_x2(ssq);

        const float alpha = 1.f / denom;
        const float n2    = ssq * alpha * alpha;
        const float nrm   = sqrtf(n2);
        const float coeff = (n2 / (1.f + n2)) / (nrm + EPS);
        const float beta  = alpha * coeff;        // v[d] = s_unnorm[d] * beta

        if (it < 2) {
            // ---- u[g,k]: pk-packed d-slice dot + DPP quad reduce ----
            const v2f beta2 = mk2(beta, beta);
            const v2f t01 = pk_mul(s01, beta2);
            const v2f t23 = pk_mul(s23, beta2);
            float uk[8];
            #pragma unroll
            for (int k = 0; k < 8; ++k) {
                const float4 wv = *(const float4*)(wg + k * 16);
                v2f uu2 = pk_mul(t01, mk2(wv.x, wv.y));
                uu2 = pk_fma(t23, mk2(wv.z, wv.w), uu2);
                float uu = uu2.x + uu2.y;
                uu = dpp_add_x1(uu);
                uk[k] = dpp_add_x2(uu);
            }
            float u8;
            {
                const float4 wb = *(const float4*)(wg + 128);
                v2f uu2 = pk_mul(t01, mk2(wb.x, wb.y));
                uu2 = pk_fma(t23, mk2(wb.z, wb.w), uu2);
                u8 = uu2.x + uu2.y;
                u8 = dpp_add_x1(u8);
                u8 = dpp_add_x2(u8);
            }
            // ---- b-update, packed ----
            const v2f u82 = mk2(u8, u8);
            #pragma unroll
            for (int p = 0; p < 4; ++p) bl2[p] = pk_add(bl2[p], u82);
            #pragma unroll
            for (int k = 0; k < 8; ++k) {
                const v2f uk2 = mk2(uk[k], uk[k]);
                #pragma unroll
                for (int p = 0; p < 4; ++p)
                    bl2[p] = pk_fma(uk2, xq2[k][p], bl2[p]);
            }
            float acc8 = u8;
            #pragma unroll
            for (int k = 0; k < 8; ++k) acc8 += uk[k] * xq8[k];
            bl8 += acc8;
        } else {
            if (t < D_) {
                const float sd = swl[kb][0][t] + swl[kb][1][t];
                out[(size_t)bj * D_ + t] = sd * beta;
            }
        }
    }
}

extern "C" void kernel_launch(void* const* d_in, const int* in_sizes, int n_in,
                              void* d_out, int out_size, void* d_ws, size_t ws_size,
                              hipStream_t stream) {
    const float* x    = (const float*)d_in[0];
    const float* Wt   = (const float*)d_in[1];
    const float* bias = (const float*)d_in[2];
    float* out        = (float*)d_out;

    const int bs = in_sizes[0] / 9216;   // 256
    dim3 grid(bs * J_);                  // 2560
    dim3 block(NT_);
    caps_route_kernel<<<grid, block, 0, stream>>>(x, Wt, bias, out);
}

// Round 18
// 21.119 us; speedup vs baseline: 1.0040x; 1.0040x over previous
//
#include <hip/hip_runtime.h>
#include <math.h>

// CapLayer fused, R18 = R17 + permlane16_swap for xor16 (last DS-pipe op on
// the per-iter reduce chain; VALU-pipe like R17's validated permlane32) +
// bias-row b128 hoisted to once/iter. Minimal diff; if neutral, this
// structure is at its latency floor (VALU ~7us, DS ~5us, latency the rest).
// NO launch_bounds min-waves (R2/R3/R7: caps below working set spill).

#define G_    32
#define J_    10
#define D_    16
#define NT_   128
#define GSW_  148

typedef float v2f __attribute__((ext_vector_type(2)));

__device__ __forceinline__ v2f pk_fma(v2f a, v2f b, v2f c) {
    v2f d;
    asm("v_pk_fma_f32 %0, %1, %2, %3" : "=v"(d) : "v"(a), "v"(b), "v"(c));
    return d;
}
__device__ __forceinline__ v2f pk_add(v2f a, v2f b) {
    v2f d;
    asm("v_pk_add_f32 %0, %1, %2" : "=v"(d) : "v"(a), "v"(b));
    return d;
}
__device__ __forceinline__ v2f pk_mul(v2f a, v2f b) {
    v2f d;
    asm("v_pk_mul_f32 %0, %1, %2" : "=v"(d) : "v"(a), "v"(b));
    return d;
}
__device__ __forceinline__ v2f mk2(float a, float b) { v2f r; r.x = a; r.y = b; return r; }

__device__ __forceinline__ float dpp_add_x1(float v) {   // v += lane^1
    const int s = __builtin_amdgcn_update_dpp(0, __float_as_int(v), 0xB1, 0xF, 0xF, true);
    return v + __int_as_float(s);
}
__device__ __forceinline__ float dpp_add_x2(float v) {   // v += lane^2
    const int s = __builtin_amdgcn_update_dpp(0, __float_as_int(v), 0x4E, 0xF, 0xF, true);
    return v + __int_as_float(s);
}
__device__ __forceinline__ float dpp_add_ror4(float v) { // v += row_ror:4
    const int s = __builtin_amdgcn_update_dpp(0, __float_as_int(v), 0x124, 0xF, 0xF, true);
    return v + __int_as_float(s);
}
__device__ __forceinline__ float dpp_add_ror8(float v) { // v += row_ror:8
    const int s = __builtin_amdgcn_update_dpp(0, __float_as_int(v), 0x128, 0xF, 0xF, true);
    return v + __int_as_float(s);
}
__device__ __forceinline__ float pl32_add(float v) {     // v += lane^32 (VALU)
    float a = v, b = v;
    asm("v_permlane32_swap_b32 %0, %1" : "+v"(a), "+v"(b));
    return a + b;
}
__device__ __forceinline__ float pl16_add(float v) {     // v += lane^16 (VALU)
    float a = v, b = v;
    asm("v_permlane16_swap_b32 %0, %1" : "+v"(a), "+v"(b));
    return a + b;   // a=[r0,r0,r2,r2], b=[r1,r1,r3,r3] -> a+b = xor16 sum
}

__global__ __launch_bounds__(NT_) void caps_route_kernel(
    const float* __restrict__ x,     // (b, g*8+k, s) flat b*9216 + g*288 + k*36 + s
    const float* __restrict__ Wt,    // (g, j*16+d, k) flat g*1280 + (j*16+d)*8 + k
    const float* __restrict__ bias,  // g*160 + j*16 + d
    float* __restrict__ out)         // (b, j, d)
{
    const int B = blockIdx.x, nwg = gridDim.x;
    const int bj = ((nwg & 7) == 0) ? (B & 7) * (nwg >> 3) + (B >> 3) : B;
    const int b = bj / J_, j = bj - b * J_;
    const int t = threadIdx.x;
    const int lane = t & 63, wid = t >> 6;
    const int g = t >> 2, c = t & 3;     // group 0..31, 4 lanes/group

    __shared__ float Wk[G_ * GSW_];               // 18.9 KB, [g][k][d] (+bias k=8)
    __shared__ __align__(16) float swl[2][2][D_]; // [buf][wave][d] s-partials
    __shared__ float esw[2][2];                   // [buf][wave] exp-sum partials

    // ---- x preload as q-pairs ----
    v2f  xq2[8][4];
    float xq8[8];
    {
        const float* xb = x + (size_t)b * 9216 + (size_t)g * 288 + 4 * c;
        #pragma unroll
        for (int k = 0; k < 8; ++k) {
            const float4 a0 = *(const float4*)(xb + k * 36);
            const float4 a1 = *(const float4*)(xb + k * 36 + 16);
            xq2[k][0] = mk2(a0.x, a0.y); xq2[k][1] = mk2(a0.z, a0.w);
            xq2[k][2] = mk2(a1.x, a1.y); xq2[k][3] = mk2(a1.z, a1.w);
            xq8[k] = xb[k * 36 + 32 - 3 * c];   // = row + 32 + c
        }
    }

    // ---- stage Wk transposed ([g][k][d]) + bias as k=8 row ----
    #pragma unroll
    for (int rr = 0; rr < 4; ++rr) {
        const int idx = t + rr * NT_;
        const int gg = idx >> 4, d = idx & 15;
        const float* src = Wt + (size_t)gg * 1280 + j * 128 + d * 8;
        const float4 a0 = *(const float4*)(src);
        const float4 a1 = *(const float4*)(src + 4);
        float* dst = Wk + gg * GSW_ + d;
        dst[0]   = a0.x; dst[16]  = a0.y; dst[32]  = a0.z; dst[48]  = a0.w;
        dst[64]  = a1.x; dst[80]  = a1.y; dst[96]  = a1.z; dst[112] = a1.w;
        dst[128] = bias[gg * 160 + j * 16 + d];
    }
    __syncthreads();                               // barrier 0 (staging)

    v2f  bl2[4] = {mk2(0.f,0.f), mk2(0.f,0.f), mk2(0.f,0.f), mk2(0.f,0.f)};
    float bl8 = 0.f;
    const float EPS = 2.220446049250313e-16f;

    #pragma unroll 1
    for (int it = 0; it < 3; ++it) {
        const int kb = it & 1;
        const float* wg = Wk + g * GSW_ + 4 * c;
        const float4 wb = *(const float4*)(wg + 128);  // bias row, once/iter

        // ---- e-weighted x sums (packed) ----
        float yp[8];
        float esum = 0.f;
        if (it == 0) {
            #pragma unroll
            for (int k = 0; k < 8; ++k) {
                v2f acc = pk_add(xq2[k][0], xq2[k][1]);
                acc = pk_add(acc, xq2[k][2]);
                acc = pk_add(acc, xq2[k][3]);
                yp[k] = acc.x + acc.y + xq8[k];
            }
        } else {
            v2f e2[4];
            #pragma unroll
            for (int p = 0; p < 4; ++p)
                e2[p] = mk2(__expf(bl2[p].x), __expf(bl2[p].y));
            const float e8 = __expf(bl8);
            v2f es2 = pk_add(pk_add(e2[0], e2[1]), pk_add(e2[2], e2[3]));
            esum = es2.x + es2.y + e8;
            #pragma unroll
            for (int k = 0; k < 8; ++k) {
                v2f acc = pk_mul(e2[0], xq2[k][0]);
                acc = pk_fma(e2[1], xq2[k][1], acc);
                acc = pk_fma(e2[2], xq2[k][2], acc);
                acc = pk_fma(e2[3], xq2[k][3], acc);
                yp[k] = acc.x + acc.y + e8 * xq8[k];
            }
        }
        // quad reduce via DPP
        #pragma unroll
        for (int k = 0; k < 8; ++k) {
            yp[k] = dpp_add_x1(yp[k]);
            yp[k] = dpp_add_x2(yp[k]);
        }
        if (it > 0) { esum = dpp_add_x1(esum); esum = dpp_add_x2(esum); }
        const float cg = (it == 0) ? 36.f : esum;

        // ---- per-lane s-partial for d = 4c..4c+3, pk-packed over d-pairs ----
        v2f part01, part23;
        {
            const v2f cg2 = mk2(cg, cg);
            part01 = pk_mul(mk2(wb.x, wb.y), cg2);
            part23 = pk_mul(mk2(wb.z, wb.w), cg2);
            #pragma unroll
            for (int k = 0; k < 8; ++k) {
                const float4 wv = *(const float4*)(wg + k * 16);
                const v2f yp2 = mk2(yp[k], yp[k]);
                part01 = pk_fma(mk2(wv.x, wv.y), yp2, part01);
                part23 = pk_fma(mk2(wv.z, wv.w), yp2, part23);
            }
        }
        float part[4];
        part[0] = part01.x; part[1] = part01.y;
        part[2] = part23.x; part[3] = part23.y;
        // reduce over the wave's 16 groups: all VALU now
        // (ror4/ror8 DPP, permlane16_swap, permlane32_swap — zero DS)
        #pragma unroll
        for (int m = 0; m < 4; ++m) {
            part[m] = dpp_add_ror4(part[m]);
            part[m] = dpp_add_ror8(part[m]);
            part[m] = pl16_add(part[m]);
            part[m] = pl32_add(part[m]);
        }
        if (it > 0) {
            esum = dpp_add_ror4(esum);
            esum = dpp_add_ror8(esum);
            esum = pl16_add(esum);
            esum = pl32_add(esum);
        }
        // lanes 0..3 hold s_w[4c..4c+3] (c == lane there)
        if (lane < 4) {
            float4 pw; pw.x = part[0]; pw.y = part[1]; pw.z = part[2]; pw.w = part[3];
            *(float4*)(&swl[kb][wid][4 * lane]) = pw;
            if (lane == 0) esw[kb][wid] = esum;
        }
        __syncthreads();                           // 1 barrier per iter

        const float denom = (it == 0) ? 1152.f : (esw[kb][0] + esw[kb][1]);

        // ---- this lane's s d-slice (broadcast b128 reads), pk-packed ----
        const float4 sa = *(const float4*)(&swl[kb][0][4 * c]);
        const float4 sb = *(const float4*)(&swl[kb][1][4 * c]);
        const v2f s01 = pk_add(mk2(sa.x, sa.y), mk2(sb.x, sb.y));
        const v2f s23 = pk_add(mk2(sa.z, sa.w), mk2(sb.z, sb.w));

        // ssq: slice partial + DPP quad reduce
        v2f ss2 = pk_mul(s01, s01);
        ss2 = pk_fma(s23, s23, ss2);
        float ssq = ss2.x + ss2.y;
        ssq = dpp_add_x1(ssq);
        ssq = dpp_add_x2(ssq);

        const float alpha = 1.f / denom;
        const float n2    = ssq * alpha * alpha;
        const float nrm   = sqrtf(n2);
        const float coeff = (n2 / (1.f + n2)) / (nrm + EPS);
        const float beta  = alpha * coeff;        // v[d] = s_unnorm[d] * beta

        if (it < 2) {
            // ---- u[g,k]: pk-packed d-slice dot + DPP quad reduce ----
            const v2f beta2 = mk2(beta, beta);
            const v2f t01 = pk_mul(s01, beta2);
            const v2f t23 = pk_mul(s23, beta2);
            float uk[8];
            #pragma unroll
            for (int k = 0; k < 8; ++k) {
                const float4 wv = *(const float4*)(wg + k * 16);
                v2f uu2 = pk_mul(t01, mk2(wv.x, wv.y));
                uu2 = pk_fma(t23, mk2(wv.z, wv.w), uu2);
                float uu = uu2.x + uu2.y;
                uu = dpp_add_x1(uu);
                uk[k] = dpp_add_x2(uu);
            }
            float u8;
            {
                v2f uu2 = pk_mul(t01, mk2(wb.x, wb.y));
                uu2 = pk_fma(t23, mk2(wb.z, wb.w), uu2);
                u8 = uu2.x + uu2.y;
                u8 = dpp_add_x1(u8);
                u8 = dpp_add_x2(u8);
            }
            // ---- b-update, packed ----
            const v2f u82 = mk2(u8, u8);
            #pragma unroll
            for (int p = 0; p < 4; ++p) bl2[p] = pk_add(bl2[p], u82);
            #pragma unroll
            for (int k = 0; k < 8; ++k) {
                const v2f uk2 = mk2(uk[k], uk[k]);
                #pragma unroll
                for (int p = 0; p < 4; ++p)
                    bl2[p] = pk_fma(uk2, xq2[k][p], bl2[p]);
            }
            float acc8 = u8;
            #pragma unroll
            for (int k = 0; k < 8; ++k) acc8 += uk[k] * xq8[k];
            bl8 += acc8;
        } else {
            if (t < D_) {
                const float sd = swl[kb][0][t] + swl[kb][1][t];
                out[(size_t)bj * D_ + t] = sd * beta;
            }
        }
    }
}

extern "C" void kernel_launch(void* const* d_in, const int* in_sizes, int n_in,
                              void* d_out, int out_size, void* d_ws, size_t ws_size,
                              hipStream_t stream) {
    const float* x    = (const float*)d_in[0];
    const float* Wt   = (const float*)d_in[1];
    const float* bias = (const float*)d_in[2];
    float* out        = (float*)d_out;

    const int bs = in_sizes[0] / 9216;   // 256
    dim3 grid(bs * J_);                  // 2560
    dim3 block(NT_);
    caps_route_kernel<<<grid, block, 0, stream>>>(x, Wt, bias, out);
}